// Round 1
// baseline (434.913 us; speedup 1.0000x reference)
//
#include <hip/hip_runtime.h>

// Problem geometry: x is (F=64, A=128, C=2, N=4096) fp32.
// rows = F*A*C = 16384 independent signals of length 4096.
// Each row -> 1x3 conv -> 4094 outputs, weights chosen by channel (row & 1).
// Output layout: flat (row * 4094 + n), matching merged.reshape(F, -1).
//
// V2 (this round): phase-aligned dwordx4 stores + 8B halo loads.
//  - Odd rows: out base = row*4094 ≡ 2 (mod 4 floats). Threads own outputs
//    [4c-2, 4c+2) so the store address is 16B-aligned -> ONE dwordx4 store
//    (was 2x dwordx2 half-density streams).
//  - Halo is an 8B float2 load (was a fully-redundant dwordx4): L1-side read
//    amplification 2.0x -> 1.5x, VMEM instrs per 16B unique: 4 -> 3.
//  - One row per block, 4 strided chunks per thread: every load/store
//    instruction is a dense, contiguous 64-lane stream; weight select is
//    scalar (row = blockIdx.x is wave-uniform).

#define N_IN 4096
#define N_OUT 4094
#define ROWS 16384            // 64 * 128 * 2

__global__ __launch_bounds__(256) void RTGRFID_51539607553079_kernel(
    const float* __restrict__ x,
    const float* __restrict__ w_rssi,  const float* __restrict__ b_rssi,
    const float* __restrict__ w_phase, const float* __restrict__ b_phase,
    float* __restrict__ out)
{
    const int row = blockIdx.x;           // one row per block
    const int t   = threadIdx.x;          // 0..255
    const int ch  = row & 1;              // block-uniform -> scalar selects

    const float* wsel = ch ? w_phase : w_rssi;
    const float w0 = wsel[0];
    const float w1 = wsel[1];
    const float w2 = wsel[2];
    const float b  = ch ? b_phase[0] : b_rssi[0];

    // Input row base is 16 KiB-aligned -> float4 loads are aligned.
    const float4* in4 = (const float4*)(x + (size_t)row * N_IN);
    const float2* in2 = (const float2*)in4;
    float* outr = out + (size_t)row * N_OUT;

    if (ch == 0) {
        // Even row: outr is 16B-aligned (row*4094 ≡ 0 mod 4).
        // Thread chunk c owns outputs [4c, 4c+4); needs s[4c .. 4c+5].
        #pragma unroll
        for (int k = 0; k < 4; ++k) {
            const int c = t + (k << 8);          // 0..1023, dense across lanes
            const float4 a = in4[c];             // s[4c .. 4c+3]
            if (c < 1023) {
                const float2 h = in2[2 * c + 2]; // s[4c+4], s[4c+5] (8B, L1-hit)
                float4 o;
                o.x = fmaf(w0, a.x, fmaf(w1, a.y, fmaf(w2, a.z, b)));
                o.y = fmaf(w0, a.y, fmaf(w1, a.z, fmaf(w2, a.w, b)));
                o.z = fmaf(w0, a.z, fmaf(w1, a.w, fmaf(w2, h.x, b)));
                o.w = fmaf(w0, a.w, fmaf(w1, h.x, fmaf(w2, h.y, b)));
                *(float4*)(outr + 4 * c) = o;    // 16B-aligned dense store
            } else {
                // c == 1023: only outputs 4092/4093 exist; both from `a` alone.
                float2 o;
                o.x = fmaf(w0, a.x, fmaf(w1, a.y, fmaf(w2, a.z, b)));
                o.y = fmaf(w0, a.y, fmaf(w1, a.z, fmaf(w2, a.w, b)));
                *(float2*)(outr + 4092) = o;     // ≡ 0 mod 4 -> aligned
            }
        }
    } else {
        // Odd row: outr ≡ 2 (mod 4 floats) -> shift ownership by -2 so the
        // dwordx4 store at outr + 4c - 2 is 16B-aligned.
        // Thread chunk c (c>=1) owns outputs [4c-2, 4c+2); needs s[4c-2 .. 4c+3].
        #pragma unroll
        for (int k = 0; k < 4; ++k) {
            const int c = t + (k << 8);
            const float4 a = in4[c];             // s[4c .. 4c+3]
            if (c > 0) {
                const float2 p = in2[2 * c - 1]; // s[4c-2], s[4c-1] (8B, L1-hit)
                float4 o;
                o.x = fmaf(w0, p.x, fmaf(w1, p.y, fmaf(w2, a.x, b)));  // out[4c-2]
                o.y = fmaf(w0, p.y, fmaf(w1, a.x, fmaf(w2, a.y, b)));  // out[4c-1]
                o.z = fmaf(w0, a.x, fmaf(w1, a.y, fmaf(w2, a.z, b)));  // out[4c]
                o.w = fmaf(w0, a.y, fmaf(w1, a.z, fmaf(w2, a.w, b)));  // out[4c+1]
                *(float4*)(outr + 4 * c - 2) = o; // (2 + 4c - 2) ≡ 0 mod 4 ✓
            } else {
                // c == 0: head outputs 0,1 from s[0..3].
                float2 o;
                o.x = fmaf(w0, a.x, fmaf(w1, a.y, fmaf(w2, a.z, b)));
                o.y = fmaf(w0, a.y, fmaf(w1, a.z, fmaf(w2, a.w, b)));
                *(float2*)(outr) = o;            // ≡ 2 mod 4 -> 8B-aligned ✓
            }
        }
    }
}

extern "C" void kernel_launch(void* const* d_in, const int* in_sizes, int n_in,
                              void* d_out, int out_size, void* d_ws, size_t ws_size,
                              hipStream_t stream) {
    const float* x       = (const float*)d_in[0];
    const float* w_rssi  = (const float*)d_in[1];
    const float* b_rssi  = (const float*)d_in[2];
    const float* w_phase = (const float*)d_in[3];
    const float* b_phase = (const float*)d_in[4];
    float* out = (float*)d_out;

    const unsigned grid  = ROWS;   // one row per block
    const unsigned block = 256;    // 4 chunks of 4 outputs per thread

    RTGRFID_51539607553079_kernel<<<grid, block, 0, stream>>>(
        x, w_rssi, b_rssi, w_phase, b_phase, out);
}